// Round 1
// baseline (348.257 us; speedup 1.0000x reference)
//
#include <hip/hip_runtime.h>
#include <math.h>

// GCN forward: h1 = relu(norm_agg(x@W1)+b1); h2 = norm_agg(h1@W2)+b2;
// g = mean_pool(h2, batch); out = g@Wl + bl.
// norm_agg uses D^-1/2 (A+I) D^-1/2 with self-loops, built as CSR-by-dst (pull).

#define FEAT1 128
#define FEAT2 64

// ---------------- degree / CSR build ----------------

__global__ void hist_kernel(const int* __restrict__ dst, int ne, int* __restrict__ deg) {
    int e = blockIdx.x * 256 + threadIdx.x;
    if (e < ne) atomicAdd(&deg[dst[e]], 1);
}

__global__ void dinv_kernel(const int* __restrict__ deg, float* __restrict__ dinv, int n) {
    int i = blockIdx.x * 256 + threadIdx.x;
    if (i < n) {
        double d = (double)(deg[i] + 1);   // +1 self loop
        dinv[i] = (float)(1.0 / sqrt(d));
    }
}

// block-level inclusive scan of deg (1024 elems / block) + per-block totals
__global__ __launch_bounds__(1024) void scan_blocks(const int* __restrict__ deg, int n,
                                                    int* __restrict__ incl, int* __restrict__ bsum) {
    __shared__ int s[1024];
    int t = threadIdx.x;
    int gid = blockIdx.x * 1024 + t;
    s[t] = (gid < n) ? deg[gid] : 0;
    __syncthreads();
    for (int off = 1; off < 1024; off <<= 1) {
        int v = (t >= off) ? s[t - off] : 0;
        __syncthreads();
        s[t] += v;
        __syncthreads();
    }
    if (gid < n) incl[gid] = s[t];
    if (t == 1023) bsum[blockIdx.x] = s[1023];
}

// exclusive scan of the (<=64) block sums
__global__ void scan_bsum(int* __restrict__ bsum, int nb) {
    __shared__ int s[64];
    int t = threadIdx.x;
    s[t] = (t < nb) ? bsum[t] : 0;
    __syncthreads();
    for (int off = 1; off < 64; off <<= 1) {
        int v = (t >= off) ? s[t - off] : 0;
        __syncthreads();
        s[t] += v;
        __syncthreads();
    }
    if (t < nb) bsum[t] = (t == 0) ? 0 : s[t - 1];
}

__global__ void finalize_offsets(const int* __restrict__ incl, const int* __restrict__ bsum,
                                 int n, int* __restrict__ offsets, int* __restrict__ cursor) {
    int gid = blockIdx.x * 256 + threadIdx.x;
    if (gid <= n) {
        int v = (gid == 0) ? 0 : (incl[gid - 1] + bsum[(gid - 1) >> 10]);
        offsets[gid] = v;
        if (gid < n) cursor[gid] = v;
    }
}

__global__ void fill_kernel(const int* __restrict__ src, const int* __restrict__ dst, int ne,
                            int* __restrict__ cursor, int* __restrict__ csr_src) {
    int e = blockIdx.x * 256 + threadIdx.x;
    if (e < ne) {
        int d = dst[e];
        int p = atomicAdd(&cursor[d], 1);
        csr_src[p] = src[e];
    }
}

// ---------------- dense GEMMs ----------------

// out[n, FOUT] = in[n, 128] @ W[128, FOUT]; 8 rows per block, FOUT threads
template <int FOUT>
__global__ __launch_bounds__(FOUT) void gemm_rows(const float* __restrict__ in,
                                                  const float* __restrict__ W,
                                                  float* __restrict__ out, int n) {
    __shared__ float xs[8][128];
    int row0 = blockIdx.x * 8;
    int f = threadIdx.x;
    #pragma unroll
    for (int r = 0; r < 8; r++) {
        #pragma unroll
        for (int p = 0; p < 128 / FOUT; p++) {
            int col = p * FOUT + f;
            xs[r][col] = (row0 + r < n) ? in[(size_t)(row0 + r) * 128 + col] : 0.0f;
        }
    }
    __syncthreads();
    float acc[8] = {0.f, 0.f, 0.f, 0.f, 0.f, 0.f, 0.f, 0.f};
    #pragma unroll 4
    for (int k = 0; k < 128; k++) {
        float w = W[k * FOUT + f];
        #pragma unroll
        for (int r = 0; r < 8; r++) acc[r] += xs[r][k] * w;
    }
    #pragma unroll
    for (int r = 0; r < 8; r++)
        if (row0 + r < n) out[(size_t)(row0 + r) * FOUT + f] = acc[r];
}

// ---------------- normalized aggregation (pull over CSR) ----------------

template <int F, bool RELU>
__global__ __launch_bounds__(F) void aggregate(const float* __restrict__ t,
                                               const float* __restrict__ dinv,
                                               const int* __restrict__ offsets,
                                               const int* __restrict__ csr_src,
                                               const float* __restrict__ bias,
                                               float* __restrict__ out) {
    int i = blockIdx.x;
    int f = threadIdx.x;
    float di = dinv[i];
    float acc = t[(size_t)i * F + f] * (di * di);      // self loop
    int e0 = offsets[i], e1 = offsets[i + 1];
    for (int e = e0; e < e1; e++) {
        int s = csr_src[e];
        float norm = dinv[s] * di;
        acc += t[(size_t)s * F + f] * norm;
    }
    acc += bias[f];
    if (RELU) acc = fmaxf(acc, 0.0f);
    out[(size_t)i * F + f] = acc;
}

// ---------------- pooling + classifier ----------------

__global__ __launch_bounds__(64) void pool_kernel(const float* __restrict__ h2,
                                                  const int* __restrict__ batch, int n,
                                                  float* __restrict__ pooled) {
    int g = blockIdx.x;
    int f = threadIdx.x;
    // boundaries in sorted batch: [start, end)
    int lo = 0, hi = n;
    while (lo < hi) { int mid = (lo + hi) >> 1; if (batch[mid] < g) lo = mid + 1; else hi = mid; }
    int start = lo;
    hi = n;
    while (lo < hi) { int mid = (lo + hi) >> 1; if (batch[mid] < g + 1) lo = mid + 1; else hi = mid; }
    int end = lo;
    float sum = 0.0f;
    for (int nn = start; nn < end; nn++) sum += h2[(size_t)nn * 64 + f];
    float cnt = (float)(end - start);
    pooled[g * 64 + f] = sum / fmaxf(cnt, 1.0f);
}

__global__ __launch_bounds__(64) void final_gemm(const float* __restrict__ pooled,
                                                 const float* __restrict__ Wl,
                                                 const float* __restrict__ bl,
                                                 float* __restrict__ out) {
    int g = blockIdx.x;
    int f = threadIdx.x;
    float acc = bl[f];
    #pragma unroll 4
    for (int k = 0; k < 64; k++) acc += pooled[g * 64 + k] * Wl[k * 64 + f];
    out[g * 64 + f] = acc;
}

// ---------------- launch ----------------

extern "C" void kernel_launch(void* const* d_in, const int* in_sizes, int n_in,
                              void* d_out, int out_size, void* d_ws, size_t ws_size,
                              hipStream_t stream) {
    const float* x    = (const float*)d_in[0];
    const int*   eidx = (const int*)d_in[1];
    const int*   batch= (const int*)d_in[2];
    const float* W1   = (const float*)d_in[3];
    const float* b1   = (const float*)d_in[4];
    const float* W2   = (const float*)d_in[5];
    const float* b2   = (const float*)d_in[6];
    const float* Wl   = (const float*)d_in[7];
    const float* bl   = (const float*)d_in[8];
    float* out = (float*)d_out;

    const int n_nodes  = in_sizes[0] / FEAT1;     // 50000
    const int n_edges  = in_sizes[1] / 2;         // 800000
    const int n_graphs = out_size / FEAT2;        // 512
    const int* esrc = eidx;
    const int* edst = eidx + n_edges;

    // workspace layout
    char* ws = (char*)d_ws;
    size_t off = 0;
    auto alloc = [&](size_t bytes) -> void* {
        void* p = ws + off;
        off += (bytes + 255) & ~(size_t)255;
        return p;
    };
    float* t1      = (float*)alloc((size_t)n_nodes * FEAT1 * 4);  // also reused as t2
    float* hb      = (float*)alloc((size_t)n_nodes * FEAT1 * 4);  // h, reused as h2
    float* dinv    = (float*)alloc((size_t)n_nodes * 4);
    int*   deg     = (int*)alloc((size_t)n_nodes * 4);
    int*   incl    = (int*)alloc((size_t)n_nodes * 4);
    int*   offsets = (int*)alloc((size_t)(n_nodes + 1) * 4);
    int*   cursor  = (int*)alloc((size_t)n_nodes * 4);
    int*   bsum    = (int*)alloc(256);
    int*   csr     = (int*)alloc((size_t)n_edges * 4);
    float* pooled  = (float*)alloc((size_t)n_graphs * FEAT2 * 4);

    const int nb_scan = (n_nodes + 1023) / 1024;  // 49

    // 1. degree histogram (+ self loop handled in dinv)
    hipMemsetAsync(deg, 0, (size_t)n_nodes * 4, stream);
    hist_kernel<<<(n_edges + 255) / 256, 256, 0, stream>>>(edst, n_edges, deg);
    dinv_kernel<<<(n_nodes + 255) / 256, 256, 0, stream>>>(deg, dinv, n_nodes);

    // 2. CSR by dst
    scan_blocks<<<nb_scan, 1024, 0, stream>>>(deg, n_nodes, incl, bsum);
    scan_bsum<<<1, 64, 0, stream>>>(bsum, nb_scan);
    finalize_offsets<<<(n_nodes + 256) / 256, 256, 0, stream>>>(incl, bsum, n_nodes, offsets, cursor);
    fill_kernel<<<(n_edges + 255) / 256, 256, 0, stream>>>(esrc, edst, n_edges, cursor, csr);

    // 3. layer 1: t1 = x @ W1 ; h = relu(agg(t1) + b1)
    gemm_rows<FEAT1><<<(n_nodes + 7) / 8, FEAT1, 0, stream>>>(x, W1, t1, n_nodes);
    aggregate<FEAT1, true><<<n_nodes, FEAT1, 0, stream>>>(t1, dinv, offsets, csr, b1, hb);

    // 4. layer 2: t2 = h @ W2 ; h2 = agg(t2) + b2   (t2 reuses t1 buffer, h2 reuses hb)
    gemm_rows<FEAT2><<<(n_nodes + 7) / 8, FEAT2, 0, stream>>>(hb, W2, t1, n_nodes);
    aggregate<FEAT2, false><<<n_nodes, FEAT2, 0, stream>>>(t1, dinv, offsets, csr, b2, hb);

    // 5. mean pool per graph + classifier
    pool_kernel<<<n_graphs, 64, 0, stream>>>(hb, batch, n_nodes, pooled);
    final_gemm<<<n_graphs, 64, 0, stream>>>(pooled, Wl, bl, out);
}

// Round 2
// 288.755 us; speedup vs baseline: 1.2061x; 1.2061x over previous
//
#include <hip/hip_runtime.h>
#include <math.h>

// GCN forward: h1 = relu(norm_agg(x@W1)+b1); h2 = norm_agg(h1@W2)+b2;
// g = mean_pool(h2, batch); out = g@Wl + bl.
// norm_agg uses D^-1/2 (A+I) D^-1/2 with self-loops, built as CSR-by-dst (pull).

#define FEAT1 128
#define FEAT2 64

// ---------------- degree / CSR build ----------------

__global__ void hist_kernel(const int* __restrict__ dst, int ne, int* __restrict__ deg) {
    int e = blockIdx.x * 256 + threadIdx.x;
    if (e < ne) atomicAdd(&deg[dst[e]], 1);
}

__global__ void dinv_kernel(const int* __restrict__ deg, float* __restrict__ dinv, int n) {
    int i = blockIdx.x * 256 + threadIdx.x;
    if (i < n) {
        double d = (double)(deg[i] + 1);   // +1 self loop
        dinv[i] = (float)(1.0 / sqrt(d));
    }
}

// block-level inclusive scan of deg (1024 elems / block) + per-block totals
__global__ __launch_bounds__(1024) void scan_blocks(const int* __restrict__ deg, int n,
                                                    int* __restrict__ incl, int* __restrict__ bsum) {
    __shared__ int s[1024];
    int t = threadIdx.x;
    int gid = blockIdx.x * 1024 + t;
    s[t] = (gid < n) ? deg[gid] : 0;
    __syncthreads();
    for (int off = 1; off < 1024; off <<= 1) {
        int v = (t >= off) ? s[t - off] : 0;
        __syncthreads();
        s[t] += v;
        __syncthreads();
    }
    if (gid < n) incl[gid] = s[t];
    if (t == 1023) bsum[blockIdx.x] = s[1023];
}

// exclusive scan of the (<=64) block sums
__global__ void scan_bsum(int* __restrict__ bsum, int nb) {
    __shared__ int s[64];
    int t = threadIdx.x;
    s[t] = (t < nb) ? bsum[t] : 0;
    __syncthreads();
    for (int off = 1; off < 64; off <<= 1) {
        int v = (t >= off) ? s[t - off] : 0;
        __syncthreads();
        s[t] += v;
        __syncthreads();
    }
    if (t < nb) bsum[t] = (t == 0) ? 0 : s[t - 1];
}

__global__ void finalize_offsets(const int* __restrict__ incl, const int* __restrict__ bsum,
                                 int n, int* __restrict__ offsets, int* __restrict__ cursor) {
    int gid = blockIdx.x * 256 + threadIdx.x;
    if (gid <= n) {
        int v = (gid == 0) ? 0 : (incl[gid - 1] + bsum[(gid - 1) >> 10]);
        offsets[gid] = v;
        if (gid < n) cursor[gid] = v;
    }
}

__global__ void fill_kernel(const int* __restrict__ src, const int* __restrict__ dst, int ne,
                            int* __restrict__ cursor, int* __restrict__ csr_src) {
    int e = blockIdx.x * 256 + threadIdx.x;
    if (e < ne) {
        int d = dst[e];
        int p = atomicAdd(&cursor[d], 1);
        csr_src[p] = src[e];
    }
}

// ---------------- tiled dense GEMM ----------------
// out[n, FOUT] = A[n,128] @ W[128, FOUT]
// 64x64 output tile / block (256 threads), K staged in LDS in chunks of 32.
// Each thread: 4 rows x 4 cols register tile.
template <int FOUT>
__global__ __launch_bounds__(256) void gemm_tile(const float* __restrict__ A,
                                                 const float* __restrict__ W,
                                                 float* __restrict__ out, int n) {
    __shared__ float As[64][36];   // pad 36: float4-aligned, 2-way bank alias only
    __shared__ float Ws[32][68];   // pad 68: conflict-free read + uniform write
    const int tid = threadIdx.x;
    constexpr int NCT = FOUT / 64;
    const int row0 = (blockIdx.x / NCT) * 64;
    const int col0 = (blockIdx.x % NCT) * 64;
    const int rg = tid >> 4;       // 0..15 row group (4 rows each)
    const int cg = tid & 15;       // 0..15 col group (4 cols each)

    float acc[4][4] = {};

    for (int k0 = 0; k0 < 128; k0 += 32) {
        // stage A chunk: 64 rows x 32 k (8 floats / thread)
        {
            int r = tid >> 2;               // 0..63
            int k = (tid & 3) * 8;          // 0,8,16,24
            int grow = row0 + r;
            float4 v0 = {0.f, 0.f, 0.f, 0.f}, v1 = {0.f, 0.f, 0.f, 0.f};
            if (grow < n) {
                const float* p = A + (size_t)grow * 128 + k0 + k;
                v0 = *(const float4*)(p);
                v1 = *(const float4*)(p + 4);
            }
            *(float4*)(&As[r][k])     = v0;
            *(float4*)(&As[r][k + 4]) = v1;
        }
        // stage W chunk: 32 k x 64 cols (8 floats / thread)
        {
            int k = tid >> 3;               // 0..31
            int c = (tid & 7) * 8;          // 0,8,...,56
            const float* p = W + (size_t)(k0 + k) * FOUT + col0 + c;
            *(float4*)(&Ws[k][c])     = *(const float4*)(p);
            *(float4*)(&Ws[k][c + 4]) = *(const float4*)(p + 4);
        }
        __syncthreads();

        #pragma unroll 8
        for (int k = 0; k < 32; k++) {
            float4 w = *(const float4*)(&Ws[k][cg * 4]);
            float ar0 = As[rg * 4 + 0][k];
            float ar1 = As[rg * 4 + 1][k];
            float ar2 = As[rg * 4 + 2][k];
            float ar3 = As[rg * 4 + 3][k];
            acc[0][0] += ar0 * w.x; acc[0][1] += ar0 * w.y; acc[0][2] += ar0 * w.z; acc[0][3] += ar0 * w.w;
            acc[1][0] += ar1 * w.x; acc[1][1] += ar1 * w.y; acc[1][2] += ar1 * w.z; acc[1][3] += ar1 * w.w;
            acc[2][0] += ar2 * w.x; acc[2][1] += ar2 * w.y; acc[2][2] += ar2 * w.z; acc[2][3] += ar2 * w.w;
            acc[3][0] += ar3 * w.x; acc[3][1] += ar3 * w.y; acc[3][2] += ar3 * w.z; acc[3][3] += ar3 * w.w;
        }
        __syncthreads();
    }

    #pragma unroll
    for (int rr = 0; rr < 4; rr++) {
        int grow = row0 + rg * 4 + rr;
        if (grow < n) {
            float4 v = {acc[rr][0], acc[rr][1], acc[rr][2], acc[rr][3]};
            *(float4*)(out + (size_t)grow * FOUT + col0 + cg * 4) = v;
        }
    }
}

// ---------------- normalized aggregation (pull over CSR) ----------------
// One node per WAVE (4 nodes / 256-thread block). VEC floats per lane so one
// wave-instruction reads a full feature row. Edge loop unrolled x4 with
// independent accumulators -> 4 row-gathers in flight per wave.
template <int F, bool RELU>
__global__ __launch_bounds__(256) void aggregate(const float* __restrict__ t,
                                                 const float* __restrict__ dinv,
                                                 const int* __restrict__ offsets,
                                                 const int* __restrict__ csr_src,
                                                 const float* __restrict__ bias,
                                                 float* __restrict__ out, int n) {
    constexpr int VEC = F / 64;
    const int wv = threadIdx.x >> 6;
    const int lane = threadIdx.x & 63;
    const int i = blockIdx.x * 4 + wv;
    if (i >= n) return;
    const float di = dinv[i];
    const int e0 = offsets[i], e1 = offsets[i + 1];

    float a0[VEC], a1[VEC], a2[VEC], a3[VEC];
    {
        const float* p = t + (size_t)i * F + lane * VEC;
        #pragma unroll
        for (int v = 0; v < VEC; v++) { a0[v] = p[v] * (di * di); a1[v] = 0.f; a2[v] = 0.f; a3[v] = 0.f; }
    }

    int e = e0;
    for (; e + 4 <= e1; e += 4) {
        int s0 = csr_src[e + 0], s1 = csr_src[e + 1], s2 = csr_src[e + 2], s3 = csr_src[e + 3];
        float n0 = dinv[s0] * di, n1 = dinv[s1] * di, n2 = dinv[s2] * di, n3 = dinv[s3] * di;
        if constexpr (VEC == 2) {
            float2 v0 = ((const float2*)(t + (size_t)s0 * F))[lane];
            float2 v1 = ((const float2*)(t + (size_t)s1 * F))[lane];
            float2 v2 = ((const float2*)(t + (size_t)s2 * F))[lane];
            float2 v3 = ((const float2*)(t + (size_t)s3 * F))[lane];
            a0[0] += v0.x * n0; a0[1] += v0.y * n0;
            a1[0] += v1.x * n1; a1[1] += v1.y * n1;
            a2[0] += v2.x * n2; a2[1] += v2.y * n2;
            a3[0] += v3.x * n3; a3[1] += v3.y * n3;
        } else {
            a0[0] += t[(size_t)s0 * F + lane] * n0;
            a1[0] += t[(size_t)s1 * F + lane] * n1;
            a2[0] += t[(size_t)s2 * F + lane] * n2;
            a3[0] += t[(size_t)s3 * F + lane] * n3;
        }
    }
    for (; e < e1; e++) {
        int s = csr_src[e];
        float nn = dinv[s] * di;
        if constexpr (VEC == 2) {
            float2 v = ((const float2*)(t + (size_t)s * F))[lane];
            a0[0] += v.x * nn; a0[1] += v.y * nn;
        } else {
            a0[0] += t[(size_t)s * F + lane] * nn;
        }
    }

    if constexpr (VEC == 2) {
        float2 b = ((const float2*)bias)[lane];
        float rx = a0[0] + a1[0] + a2[0] + a3[0] + b.x;
        float ry = a0[1] + a1[1] + a2[1] + a3[1] + b.y;
        if (RELU) { rx = fmaxf(rx, 0.f); ry = fmaxf(ry, 0.f); }
        ((float2*)(out + (size_t)i * F))[lane] = make_float2(rx, ry);
    } else {
        float r = a0[0] + a1[0] + a2[0] + a3[0] + bias[lane];
        if (RELU) r = fmaxf(r, 0.f);
        out[(size_t)i * F + lane] = r;
    }
}

// ---------------- pooling + classifier ----------------

__global__ __launch_bounds__(64) void pool_kernel(const float* __restrict__ h2,
                                                  const int* __restrict__ batch, int n,
                                                  float* __restrict__ pooled) {
    int g = blockIdx.x;
    int f = threadIdx.x;
    int lo = 0, hi = n;
    while (lo < hi) { int mid = (lo + hi) >> 1; if (batch[mid] < g) lo = mid + 1; else hi = mid; }
    int start = lo;
    hi = n;
    while (lo < hi) { int mid = (lo + hi) >> 1; if (batch[mid] < g + 1) lo = mid + 1; else hi = mid; }
    int end = lo;
    float sum = 0.0f;
    for (int nn = start; nn < end; nn++) sum += h2[(size_t)nn * 64 + f];
    float cnt = (float)(end - start);
    pooled[g * 64 + f] = sum / fmaxf(cnt, 1.0f);
}

__global__ __launch_bounds__(64) void final_gemm(const float* __restrict__ pooled,
                                                 const float* __restrict__ Wl,
                                                 const float* __restrict__ bl,
                                                 float* __restrict__ out) {
    int g = blockIdx.x;
    int f = threadIdx.x;
    float acc = bl[f];
    #pragma unroll 4
    for (int k = 0; k < 64; k++) acc += pooled[g * 64 + k] * Wl[k * 64 + f];
    out[g * 64 + f] = acc;
}

// ---------------- launch ----------------

extern "C" void kernel_launch(void* const* d_in, const int* in_sizes, int n_in,
                              void* d_out, int out_size, void* d_ws, size_t ws_size,
                              hipStream_t stream) {
    const float* x    = (const float*)d_in[0];
    const int*   eidx = (const int*)d_in[1];
    const int*   batch= (const int*)d_in[2];
    const float* W1   = (const float*)d_in[3];
    const float* b1   = (const float*)d_in[4];
    const float* W2   = (const float*)d_in[5];
    const float* b2   = (const float*)d_in[6];
    const float* Wl   = (const float*)d_in[7];
    const float* bl   = (const float*)d_in[8];
    float* out = (float*)d_out;

    const int n_nodes  = in_sizes[0] / FEAT1;     // 50000
    const int n_edges  = in_sizes[1] / 2;         // 800000
    const int n_graphs = out_size / FEAT2;        // 512
    const int* esrc = eidx;
    const int* edst = eidx + n_edges;

    // workspace layout
    char* ws = (char*)d_ws;
    size_t off = 0;
    auto alloc = [&](size_t bytes) -> void* {
        void* p = ws + off;
        off += (bytes + 255) & ~(size_t)255;
        return p;
    };
    float* t1      = (float*)alloc((size_t)n_nodes * FEAT1 * 4);  // also reused as t2
    float* hb      = (float*)alloc((size_t)n_nodes * FEAT1 * 4);  // h, reused as h2
    float* dinv    = (float*)alloc((size_t)n_nodes * 4);
    int*   deg     = (int*)alloc((size_t)n_nodes * 4);
    int*   incl    = (int*)alloc((size_t)n_nodes * 4);
    int*   offsets = (int*)alloc((size_t)(n_nodes + 1) * 4);
    int*   cursor  = (int*)alloc((size_t)n_nodes * 4);
    int*   bsum    = (int*)alloc(256);
    int*   csr     = (int*)alloc((size_t)n_edges * 4);
    float* pooled  = (float*)alloc((size_t)n_graphs * FEAT2 * 4);

    const int nb_scan = (n_nodes + 1023) / 1024;  // 49

    // 1. degree histogram (+ self loop handled in dinv)
    hipMemsetAsync(deg, 0, (size_t)n_nodes * 4, stream);
    hist_kernel<<<(n_edges + 255) / 256, 256, 0, stream>>>(edst, n_edges, deg);
    dinv_kernel<<<(n_nodes + 255) / 256, 256, 0, stream>>>(deg, dinv, n_nodes);

    // 2. CSR by dst
    scan_blocks<<<nb_scan, 1024, 0, stream>>>(deg, n_nodes, incl, bsum);
    scan_bsum<<<1, 64, 0, stream>>>(bsum, nb_scan);
    finalize_offsets<<<(n_nodes + 256) / 256, 256, 0, stream>>>(incl, bsum, n_nodes, offsets, cursor);
    fill_kernel<<<(n_edges + 255) / 256, 256, 0, stream>>>(esrc, edst, n_edges, cursor, csr);

    // 3. layer 1: t1 = x @ W1 ; h = relu(agg(t1) + b1)
    gemm_tile<FEAT1><<<((n_nodes + 63) / 64) * (FEAT1 / 64), 256, 0, stream>>>(x, W1, t1, n_nodes);
    aggregate<FEAT1, true><<<(n_nodes + 3) / 4, 256, 0, stream>>>(t1, dinv, offsets, csr, b1, hb, n_nodes);

    // 4. layer 2: t2 = h @ W2 ; h2 = agg(t2) + b2   (t2 reuses t1 buffer, h2 reuses hb)
    gemm_tile<FEAT2><<<((n_nodes + 63) / 64) * (FEAT2 / 64), 256, 0, stream>>>(hb, W2, t1, n_nodes);
    aggregate<FEAT2, false><<<(n_nodes + 3) / 4, 256, 0, stream>>>(t1, dinv, offsets, csr, b2, hb, n_nodes);

    // 5. mean pool per graph + classifier
    pool_kernel<<<n_graphs, 64, 0, stream>>>(hb, batch, n_nodes, pooled);
    final_gemm<<<n_graphs, 64, 0, stream>>>(pooled, Wl, bl, out);
}

// Round 3
// 259.566 us; speedup vs baseline: 1.3417x; 1.1125x over previous
//
#include <hip/hip_runtime.h>
#include <hip/hip_fp16.h>
#include <math.h>

// GCN forward: h1 = relu(norm_agg(x@W1)+b1); h2 = norm_agg(h1@W2)+b2;
// g = mean_pool(h2, batch); out = g@Wl + bl.
// norm_agg = D^-1/2 (A+I) D^-1/2, CSR-by-dst pull.
// Key R3 optimization: GEMM writes t_scaled[i] = (in@W)[i] * dinv[i] as FP16
// -> aggregate is a pure row-sum gather (half the bytes, no per-edge dinv).

#define FEAT1 128
#define FEAT2 64

// ---------------- degree / CSR build ----------------

__global__ void hist_kernel(const int* __restrict__ dst, int ne, int* __restrict__ deg) {
    int e = blockIdx.x * 256 + threadIdx.x;
    if (e < ne) atomicAdd(&deg[dst[e]], 1);
}

__global__ void dinv_kernel(const int* __restrict__ deg, float* __restrict__ dinv, int n) {
    int i = blockIdx.x * 256 + threadIdx.x;
    if (i < n) {
        double d = (double)(deg[i] + 1);   // +1 self loop
        dinv[i] = (float)(1.0 / sqrt(d));
    }
}

// block-level inclusive scan of deg (1024 elems / block) + per-block totals
__global__ __launch_bounds__(1024) void scan_blocks(const int* __restrict__ deg, int n,
                                                    int* __restrict__ incl, int* __restrict__ bsum) {
    __shared__ int s[1024];
    int t = threadIdx.x;
    int gid = blockIdx.x * 1024 + t;
    s[t] = (gid < n) ? deg[gid] : 0;
    __syncthreads();
    for (int off = 1; off < 1024; off <<= 1) {
        int v = (t >= off) ? s[t - off] : 0;
        __syncthreads();
        s[t] += v;
        __syncthreads();
    }
    if (gid < n) incl[gid] = s[t];
    if (t == 1023) bsum[blockIdx.x] = s[1023];
}

__global__ void scan_bsum(int* __restrict__ bsum, int nb) {
    __shared__ int s[64];
    int t = threadIdx.x;
    s[t] = (t < nb) ? bsum[t] : 0;
    __syncthreads();
    for (int off = 1; off < 64; off <<= 1) {
        int v = (t >= off) ? s[t - off] : 0;
        __syncthreads();
        s[t] += v;
        __syncthreads();
    }
    if (t < nb) bsum[t] = (t == 0) ? 0 : s[t - 1];
}

__global__ void finalize_offsets(const int* __restrict__ incl, const int* __restrict__ bsum,
                                 int n, int* __restrict__ offsets, int* __restrict__ cursor) {
    int gid = blockIdx.x * 256 + threadIdx.x;
    if (gid <= n) {
        int v = (gid == 0) ? 0 : (incl[gid - 1] + bsum[(gid - 1) >> 10]);
        offsets[gid] = v;
        if (gid < n) cursor[gid] = v;
    }
}

__global__ void fill_kernel(const int* __restrict__ src, const int* __restrict__ dst, int ne,
                            int* __restrict__ cursor, int* __restrict__ csr_src) {
    int e = blockIdx.x * 256 + threadIdx.x;
    if (e < ne) {
        int d = dst[e];
        int p = atomicAdd(&cursor[d], 1);
        csr_src[p] = src[e];
    }
}

// ---------------- tiled dense GEMM with fp16+dinv-scaled output ----------------
// t_out[row, c] = fp16( (A[row,:] @ W[:,c]) * dinv[row] )
// 64x64 tile / 256 threads, K in LDS chunks of 32, 4x4 register tile.
template <int FOUT>
__global__ __launch_bounds__(256) void gemm_tile_h(const float* __restrict__ A,
                                                   const float* __restrict__ W,
                                                   const float* __restrict__ dinv,
                                                   __half* __restrict__ out, int n) {
    __shared__ float As[64][36];
    __shared__ float Ws[32][68];
    const int tid = threadIdx.x;
    constexpr int NCT = FOUT / 64;
    const int row0 = (blockIdx.x / NCT) * 64;
    const int col0 = (blockIdx.x % NCT) * 64;
    const int rg = tid >> 4;
    const int cg = tid & 15;

    float acc[4][4] = {};

    for (int k0 = 0; k0 < 128; k0 += 32) {
        {
            int r = tid >> 2;
            int k = (tid & 3) * 8;
            int grow = row0 + r;
            float4 v0 = {0.f, 0.f, 0.f, 0.f}, v1 = {0.f, 0.f, 0.f, 0.f};
            if (grow < n) {
                const float* p = A + (size_t)grow * 128 + k0 + k;
                v0 = *(const float4*)(p);
                v1 = *(const float4*)(p + 4);
            }
            *(float4*)(&As[r][k])     = v0;
            *(float4*)(&As[r][k + 4]) = v1;
        }
        {
            int k = tid >> 3;
            int c = (tid & 7) * 8;
            const float* p = W + (size_t)(k0 + k) * FOUT + col0 + c;
            *(float4*)(&Ws[k][c])     = *(const float4*)(p);
            *(float4*)(&Ws[k][c + 4]) = *(const float4*)(p + 4);
        }
        __syncthreads();

        #pragma unroll 8
        for (int k = 0; k < 32; k++) {
            float4 w = *(const float4*)(&Ws[k][cg * 4]);
            float ar0 = As[rg * 4 + 0][k];
            float ar1 = As[rg * 4 + 1][k];
            float ar2 = As[rg * 4 + 2][k];
            float ar3 = As[rg * 4 + 3][k];
            acc[0][0] += ar0 * w.x; acc[0][1] += ar0 * w.y; acc[0][2] += ar0 * w.z; acc[0][3] += ar0 * w.w;
            acc[1][0] += ar1 * w.x; acc[1][1] += ar1 * w.y; acc[1][2] += ar1 * w.z; acc[1][3] += ar1 * w.w;
            acc[2][0] += ar2 * w.x; acc[2][1] += ar2 * w.y; acc[2][2] += ar2 * w.z; acc[2][3] += ar2 * w.w;
            acc[3][0] += ar3 * w.x; acc[3][1] += ar3 * w.y; acc[3][2] += ar3 * w.z; acc[3][3] += ar3 * w.w;
        }
        __syncthreads();
    }

    #pragma unroll
    for (int rr = 0; rr < 4; rr++) {
        int grow = row0 + rg * 4 + rr;
        if (grow < n) {
            float s = dinv[grow];
            __half2 h01 = __floats2half2_rn(acc[rr][0] * s, acc[rr][1] * s);
            __half2 h23 = __floats2half2_rn(acc[rr][2] * s, acc[rr][3] * s);
            __half2* p = (__half2*)(out + (size_t)grow * FOUT + col0 + cg * 4);
            p[0] = h01;
            p[1] = h23;
        }
    }
}

// ---------------- normalized aggregation: pure fp16 row-sum gather ----------------
// out[i] = relu?( (sum_{s in N(i) u {i}} t_scaled[s]) * dinv[i] + b )
// One node per wave, 4 nodes / 256-thread block, edge loop unrolled x4.
template <int F, bool RELU>
__global__ __launch_bounds__(256) void aggregate_h(const __half* __restrict__ t,
                                                   const float* __restrict__ dinv,
                                                   const int* __restrict__ offsets,
                                                   const int* __restrict__ csr_src,
                                                   const float* __restrict__ bias,
                                                   float* __restrict__ out, int n) {
    const int wv = threadIdx.x >> 6;
    const int lane = threadIdx.x & 63;
    const int i = blockIdx.x * 4 + wv;
    if (i >= n) return;
    const float di = dinv[i];
    const int e0 = offsets[i], e1 = offsets[i + 1];

    if constexpr (F == 128) {
        // 2 feature elems / lane (half2 = 4B -> one 256B wave-load per row)
        float2 a0, a1 = {0.f, 0.f}, a2 = {0.f, 0.f}, a3 = {0.f, 0.f};
        a0 = __half22float2(((const __half2*)(t + (size_t)i * F))[lane]);  // self
        int e = e0;
        for (; e + 4 <= e1; e += 4) {
            int s0 = csr_src[e + 0], s1 = csr_src[e + 1], s2 = csr_src[e + 2], s3 = csr_src[e + 3];
            float2 v0 = __half22float2(((const __half2*)(t + (size_t)s0 * F))[lane]);
            float2 v1 = __half22float2(((const __half2*)(t + (size_t)s1 * F))[lane]);
            float2 v2 = __half22float2(((const __half2*)(t + (size_t)s2 * F))[lane]);
            float2 v3 = __half22float2(((const __half2*)(t + (size_t)s3 * F))[lane]);
            a0.x += v0.x; a0.y += v0.y;
            a1.x += v1.x; a1.y += v1.y;
            a2.x += v2.x; a2.y += v2.y;
            a3.x += v3.x; a3.y += v3.y;
        }
        for (; e < e1; e++) {
            int s = csr_src[e];
            float2 v = __half22float2(((const __half2*)(t + (size_t)s * F))[lane]);
            a0.x += v.x; a0.y += v.y;
        }
        float2 b = ((const float2*)bias)[lane];
        float rx = (a0.x + a1.x + a2.x + a3.x) * di + b.x;
        float ry = (a0.y + a1.y + a2.y + a3.y) * di + b.y;
        if (RELU) { rx = fmaxf(rx, 0.f); ry = fmaxf(ry, 0.f); }
        ((float2*)(out + (size_t)i * F))[lane] = make_float2(rx, ry);
    } else {
        // F == 64: 1 half / lane (128B wave-load per row)
        float a0, a1 = 0.f, a2 = 0.f, a3 = 0.f;
        a0 = __half2float(t[(size_t)i * F + lane]);  // self
        int e = e0;
        for (; e + 4 <= e1; e += 4) {
            int s0 = csr_src[e + 0], s1 = csr_src[e + 1], s2 = csr_src[e + 2], s3 = csr_src[e + 3];
            float v0 = __half2float(t[(size_t)s0 * F + lane]);
            float v1 = __half2float(t[(size_t)s1 * F + lane]);
            float v2 = __half2float(t[(size_t)s2 * F + lane]);
            float v3 = __half2float(t[(size_t)s3 * F + lane]);
            a0 += v0; a1 += v1; a2 += v2; a3 += v3;
        }
        for (; e < e1; e++) {
            a0 += __half2float(t[(size_t)csr_src[e] * F + lane]);
        }
        float r = (a0 + a1 + a2 + a3) * di + bias[lane];
        if (RELU) r = fmaxf(r, 0.f);
        out[(size_t)i * F + lane] = r;
    }
}

// ---------------- pooling + classifier ----------------

__global__ __launch_bounds__(64) void pool_kernel(const float* __restrict__ h2,
                                                  const int* __restrict__ batch, int n,
                                                  float* __restrict__ pooled) {
    int g = blockIdx.x;
    int f = threadIdx.x;
    int lo = 0, hi = n;
    while (lo < hi) { int mid = (lo + hi) >> 1; if (batch[mid] < g) lo = mid + 1; else hi = mid; }
    int start = lo;
    hi = n;
    while (lo < hi) { int mid = (lo + hi) >> 1; if (batch[mid] < g + 1) lo = mid + 1; else hi = mid; }
    int end = lo;
    float sum = 0.0f;
    for (int nn = start; nn < end; nn++) sum += h2[(size_t)nn * 64 + f];
    float cnt = (float)(end - start);
    pooled[g * 64 + f] = sum / fmaxf(cnt, 1.0f);
}

__global__ __launch_bounds__(64) void final_gemm(const float* __restrict__ pooled,
                                                 const float* __restrict__ Wl,
                                                 const float* __restrict__ bl,
                                                 float* __restrict__ out) {
    int g = blockIdx.x;
    int f = threadIdx.x;
    float acc = bl[f];
    #pragma unroll 4
    for (int k = 0; k < 64; k++) acc += pooled[g * 64 + k] * Wl[k * 64 + f];
    out[g * 64 + f] = acc;
}

// ---------------- launch ----------------

extern "C" void kernel_launch(void* const* d_in, const int* in_sizes, int n_in,
                              void* d_out, int out_size, void* d_ws, size_t ws_size,
                              hipStream_t stream) {
    const float* x    = (const float*)d_in[0];
    const int*   eidx = (const int*)d_in[1];
    const int*   batch= (const int*)d_in[2];
    const float* W1   = (const float*)d_in[3];
    const float* b1   = (const float*)d_in[4];
    const float* W2   = (const float*)d_in[5];
    const float* b2   = (const float*)d_in[6];
    const float* Wl   = (const float*)d_in[7];
    const float* bl   = (const float*)d_in[8];
    float* out = (float*)d_out;

    const int n_nodes  = in_sizes[0] / FEAT1;     // 50000
    const int n_edges  = in_sizes[1] / 2;         // 800000
    const int n_graphs = out_size / FEAT2;        // 512
    const int* esrc = eidx;
    const int* edst = eidx + n_edges;

    // workspace layout
    char* ws = (char*)d_ws;
    size_t off = 0;
    auto alloc = [&](size_t bytes) -> void* {
        void* p = ws + off;
        off += (bytes + 255) & ~(size_t)255;
        return p;
    };
    __half* t1     = (__half*)alloc((size_t)n_nodes * FEAT1 * 2);  // fp16 scaled table (reused layer2)
    float* hb      = (float*)alloc((size_t)n_nodes * FEAT1 * 4);   // h (f32), reused as h2
    float* dinv    = (float*)alloc((size_t)n_nodes * 4);
    int*   deg     = (int*)alloc((size_t)n_nodes * 4);
    int*   incl    = (int*)alloc((size_t)n_nodes * 4);
    int*   offsets = (int*)alloc((size_t)(n_nodes + 1) * 4);
    int*   cursor  = (int*)alloc((size_t)n_nodes * 4);
    int*   bsum    = (int*)alloc(256);
    int*   csr     = (int*)alloc((size_t)n_edges * 4);
    float* pooled  = (float*)alloc((size_t)n_graphs * FEAT2 * 4);

    const int nb_scan = (n_nodes + 1023) / 1024;  // 49

    // 1. degree histogram (+ self loop handled in dinv)
    hipMemsetAsync(deg, 0, (size_t)n_nodes * 4, stream);
    hist_kernel<<<(n_edges + 255) / 256, 256, 0, stream>>>(edst, n_edges, deg);
    dinv_kernel<<<(n_nodes + 255) / 256, 256, 0, stream>>>(deg, dinv, n_nodes);

    // 2. CSR by dst
    scan_blocks<<<nb_scan, 1024, 0, stream>>>(deg, n_nodes, incl, bsum);
    scan_bsum<<<1, 64, 0, stream>>>(bsum, nb_scan);
    finalize_offsets<<<(n_nodes + 256) / 256, 256, 0, stream>>>(incl, bsum, n_nodes, offsets, cursor);
    fill_kernel<<<(n_edges + 255) / 256, 256, 0, stream>>>(esrc, edst, n_edges, cursor, csr);

    // 3. layer 1: t1 = fp16((x @ W1) * dinv) ; h = relu(agg(t1)*dinv + b1)
    gemm_tile_h<FEAT1><<<((n_nodes + 63) / 64) * (FEAT1 / 64), 256, 0, stream>>>(x, W1, dinv, t1, n_nodes);
    aggregate_h<FEAT1, true><<<(n_nodes + 3) / 4, 256, 0, stream>>>(t1, dinv, offsets, csr, b1, hb, n_nodes);

    // 4. layer 2: t2 = fp16((h @ W2) * dinv) ; h2 = agg(t2)*dinv + b2
    gemm_tile_h<FEAT2><<<((n_nodes + 63) / 64) * (FEAT2 / 64), 256, 0, stream>>>(hb, W2, dinv, t1, n_nodes);
    aggregate_h<FEAT2, false><<<(n_nodes + 3) / 4, 256, 0, stream>>>(t1, dinv, offsets, csr, b2, hb, n_nodes);

    // 5. mean pool per graph + classifier
    pool_kernel<<<n_graphs, 64, 0, stream>>>(hb, batch, n_nodes, pooled);
    final_gemm<<<n_graphs, 64, 0, stream>>>(pooled, Wl, bl, out);
}

// Round 4
// 213.530 us; speedup vs baseline: 1.6310x; 1.2156x over previous
//
#include <hip/hip_runtime.h>
#include <hip/hip_fp16.h>
#include <math.h>

// GCN forward: h1 = relu(norm_agg(x@W1)+b1); h2 = norm_agg(h1@W2)+b2;
// g = mean_pool(h2, batch); out = g@Wl + bl.
// norm_agg = D^-1/2 (A+I) D^-1/2, CSR-by-dst pull.
// R3: GEMM writes t_scaled[i] = (in@W)[i]*dinv[i] as FP16 -> aggregate is a
//     pure fp16 row-sum gather.
// R4: CSR built via 2-pass bucketed counting sort (bucket = dst>>8, fixed
//     8192-edge capacity regions). Each csr/ebin cache line is written by ONE
//     block -> kills the 16x write amplification of the atomic-ticket fill
//     (WRITE_SIZE was 51.6 MB for a 3.2 MB payload). Also folds deg/dinv/
//     offsets computation into pass 2 (13 -> 9 kernels).

#define FEAT1 128
#define FEAT2 64
#define BCAP 8192   // edge capacity per bucket; avg load = 4096 (64 sigma margin)

// ---------------- bucketed CSR build ----------------

__global__ void binit_kernel(int* __restrict__ bucket_cursor, int nb) {
    int b = blockIdx.x * 256 + threadIdx.x;
    if (b < nb) bucket_cursor[b] = b * BCAP;
}

// pass 1: scatter edges into per-bucket regions, packed src | ((dst&255)<<18)
__global__ __launch_bounds__(256) void bin_scatter(const int* __restrict__ esrc,
                                                   const int* __restrict__ edst,
                                                   int ne, int nb,
                                                   int* __restrict__ bucket_cursor,
                                                   int* __restrict__ ebin) {
    __shared__ int lcnt[256];
    __shared__ int lcur[256];
    const int tid = threadIdx.x;
    const int e0 = blockIdx.x * 8192;
    lcnt[tid] = 0;
    __syncthreads();
    #pragma unroll 4
    for (int k = 0; k < 32; k++) {
        int e = e0 + k * 256 + tid;
        if (e < ne) atomicAdd(&lcnt[edst[e] >> 8], 1);
    }
    __syncthreads();
    if (tid < nb && lcnt[tid] > 0)
        lcur[tid] = atomicAdd(&bucket_cursor[tid], lcnt[tid]);
    __syncthreads();
    #pragma unroll 4
    for (int k = 0; k < 32; k++) {
        int e = e0 + k * 256 + tid;
        if (e < ne) {
            int d = edst[e];
            int b = d >> 8;
            int p = atomicAdd(&lcur[b], 1);
            if (p < (b + 1) * BCAP)                    // capacity guard
                ebin[p] = esrc[e] | ((d & 255) << 18); // src < 2^17
        }
    }
}

// pass 2: one block per bucket. Per-node counts (LDS) -> scan -> nodeinfo
// (start,cnt) + dinv, then LDS-cursor ticket fill of csr. All csr writes for
// this bucket come from this one block -> single writeback per line.
__global__ __launch_bounds__(256) void bucket_csr(const int* __restrict__ ebin,
                                                  const int* __restrict__ bucket_cursor,
                                                  int n_nodes,
                                                  int* __restrict__ csr,
                                                  int2* __restrict__ nodeinfo,
                                                  float* __restrict__ dinv) {
    __shared__ int lcnt[256];
    __shared__ int lscan[256];
    __shared__ int lcur[256];
    const int b = blockIdx.x;
    const int tid = threadIdx.x;
    const int ebeg = b * BCAP;
    int eend = bucket_cursor[b];
    if (eend > ebeg + BCAP) eend = ebeg + BCAP;
    lcnt[tid] = 0;
    __syncthreads();
    for (int e = ebeg + tid; e < eend; e += 256)
        atomicAdd(&lcnt[(ebin[e] >> 18) & 255], 1);
    __syncthreads();
    int v = lcnt[tid];
    lscan[tid] = v;
    __syncthreads();
    for (int off = 1; off < 256; off <<= 1) {
        int u = (tid >= off) ? lscan[tid - off] : 0;
        __syncthreads();
        lscan[tid] += u;
        __syncthreads();
    }
    const int start = ebeg + (lscan[tid] - v);   // exclusive scan position
    const int node = (b << 8) + tid;
    if (node < n_nodes) {
        nodeinfo[node] = make_int2(start, v);
        dinv[node] = (float)(1.0 / sqrt((double)(v + 1)));  // +1 self loop
    }
    lcur[tid] = start;
    __syncthreads();
    for (int e = ebeg + tid; e < eend; e += 256) {
        int pk = ebin[e];
        int p = atomicAdd(&lcur[(pk >> 18) & 255], 1);
        csr[p] = pk & 0x3FFFF;
    }
}

// ---------------- tiled dense GEMM with fp16+dinv-scaled output ----------------
// t_out[row, c] = fp16( (A[row,:] @ W[:,c]) * dinv[row] )
template <int FOUT>
__global__ __launch_bounds__(256) void gemm_tile_h(const float* __restrict__ A,
                                                   const float* __restrict__ W,
                                                   const float* __restrict__ dinv,
                                                   __half* __restrict__ out, int n) {
    __shared__ float As[64][36];
    __shared__ float Ws[32][68];
    const int tid = threadIdx.x;
    constexpr int NCT = FOUT / 64;
    const int row0 = (blockIdx.x / NCT) * 64;
    const int col0 = (blockIdx.x % NCT) * 64;
    const int rg = tid >> 4;
    const int cg = tid & 15;

    float acc[4][4] = {};

    for (int k0 = 0; k0 < 128; k0 += 32) {
        {
            int r = tid >> 2;
            int k = (tid & 3) * 8;
            int grow = row0 + r;
            float4 v0 = {0.f, 0.f, 0.f, 0.f}, v1 = {0.f, 0.f, 0.f, 0.f};
            if (grow < n) {
                const float* p = A + (size_t)grow * 128 + k0 + k;
                v0 = *(const float4*)(p);
                v1 = *(const float4*)(p + 4);
            }
            *(float4*)(&As[r][k])     = v0;
            *(float4*)(&As[r][k + 4]) = v1;
        }
        {
            int k = tid >> 3;
            int c = (tid & 7) * 8;
            const float* p = W + (size_t)(k0 + k) * FOUT + col0 + c;
            *(float4*)(&Ws[k][c])     = *(const float4*)(p);
            *(float4*)(&Ws[k][c + 4]) = *(const float4*)(p + 4);
        }
        __syncthreads();

        #pragma unroll 8
        for (int k = 0; k < 32; k++) {
            float4 w = *(const float4*)(&Ws[k][cg * 4]);
            float ar0 = As[rg * 4 + 0][k];
            float ar1 = As[rg * 4 + 1][k];
            float ar2 = As[rg * 4 + 2][k];
            float ar3 = As[rg * 4 + 3][k];
            acc[0][0] += ar0 * w.x; acc[0][1] += ar0 * w.y; acc[0][2] += ar0 * w.z; acc[0][3] += ar0 * w.w;
            acc[1][0] += ar1 * w.x; acc[1][1] += ar1 * w.y; acc[1][2] += ar1 * w.z; acc[1][3] += ar1 * w.w;
            acc[2][0] += ar2 * w.x; acc[2][1] += ar2 * w.y; acc[2][2] += ar2 * w.z; acc[2][3] += ar2 * w.w;
            acc[3][0] += ar3 * w.x; acc[3][1] += ar3 * w.y; acc[3][2] += ar3 * w.z; acc[3][3] += ar3 * w.w;
        }
        __syncthreads();
    }

    #pragma unroll
    for (int rr = 0; rr < 4; rr++) {
        int grow = row0 + rg * 4 + rr;
        if (grow < n) {
            float s = dinv[grow];
            __half2 h01 = __floats2half2_rn(acc[rr][0] * s, acc[rr][1] * s);
            __half2 h23 = __floats2half2_rn(acc[rr][2] * s, acc[rr][3] * s);
            __half2* p = (__half2*)(out + (size_t)grow * FOUT + col0 + cg * 4);
            p[0] = h01;
            p[1] = h23;
        }
    }
}

// ---------------- normalized aggregation: pure fp16 row-sum gather ----------------
// out[i] = relu?( (sum_{s in N(i) u {i}} t_scaled[s]) * dinv[i] + b )
template <int F, bool RELU>
__global__ __launch_bounds__(256) void aggregate_h(const __half* __restrict__ t,
                                                   const float* __restrict__ dinv,
                                                   const int2* __restrict__ nodeinfo,
                                                   const int* __restrict__ csr_src,
                                                   const float* __restrict__ bias,
                                                   float* __restrict__ out, int n) {
    const int wv = threadIdx.x >> 6;
    const int lane = threadIdx.x & 63;
    const int i = blockIdx.x * 4 + wv;
    if (i >= n) return;
    const float di = dinv[i];
    const int2 ni = nodeinfo[i];
    const int e0 = ni.x, e1 = ni.x + ni.y;

    if constexpr (F == 128) {
        float2 a0, a1 = {0.f, 0.f}, a2 = {0.f, 0.f}, a3 = {0.f, 0.f};
        a0 = __half22float2(((const __half2*)(t + (size_t)i * F))[lane]);  // self
        int e = e0;
        for (; e + 4 <= e1; e += 4) {
            int s0 = csr_src[e + 0], s1 = csr_src[e + 1], s2 = csr_src[e + 2], s3 = csr_src[e + 3];
            float2 v0 = __half22float2(((const __half2*)(t + (size_t)s0 * F))[lane]);
            float2 v1 = __half22float2(((const __half2*)(t + (size_t)s1 * F))[lane]);
            float2 v2 = __half22float2(((const __half2*)(t + (size_t)s2 * F))[lane]);
            float2 v3 = __half22float2(((const __half2*)(t + (size_t)s3 * F))[lane]);
            a0.x += v0.x; a0.y += v0.y;
            a1.x += v1.x; a1.y += v1.y;
            a2.x += v2.x; a2.y += v2.y;
            a3.x += v3.x; a3.y += v3.y;
        }
        for (; e < e1; e++) {
            int s = csr_src[e];
            float2 v = __half22float2(((const __half2*)(t + (size_t)s * F))[lane]);
            a0.x += v.x; a0.y += v.y;
        }
        float2 b = ((const float2*)bias)[lane];
        float rx = (a0.x + a1.x + a2.x + a3.x) * di + b.x;
        float ry = (a0.y + a1.y + a2.y + a3.y) * di + b.y;
        if (RELU) { rx = fmaxf(rx, 0.f); ry = fmaxf(ry, 0.f); }
        ((float2*)(out + (size_t)i * F))[lane] = make_float2(rx, ry);
    } else {
        float a0, a1 = 0.f, a2 = 0.f, a3 = 0.f;
        a0 = __half2float(t[(size_t)i * F + lane]);  // self
        int e = e0;
        for (; e + 4 <= e1; e += 4) {
            int s0 = csr_src[e + 0], s1 = csr_src[e + 1], s2 = csr_src[e + 2], s3 = csr_src[e + 3];
            float v0 = __half2float(t[(size_t)s0 * F + lane]);
            float v1 = __half2float(t[(size_t)s1 * F + lane]);
            float v2 = __half2float(t[(size_t)s2 * F + lane]);
            float v3 = __half2float(t[(size_t)s3 * F + lane]);
            a0 += v0; a1 += v1; a2 += v2; a3 += v3;
        }
        for (; e < e1; e++) {
            a0 += __half2float(t[(size_t)csr_src[e] * F + lane]);
        }
        float r = (a0 + a1 + a2 + a3) * di + bias[lane];
        if (RELU) r = fmaxf(r, 0.f);
        out[(size_t)i * F + lane] = r;
    }
}

// ---------------- pooling + classifier ----------------

__global__ __launch_bounds__(64) void pool_kernel(const float* __restrict__ h2,
                                                  const int* __restrict__ batch, int n,
                                                  float* __restrict__ pooled) {
    int g = blockIdx.x;
    int f = threadIdx.x;
    int lo = 0, hi = n;
    while (lo < hi) { int mid = (lo + hi) >> 1; if (batch[mid] < g) lo = mid + 1; else hi = mid; }
    int start = lo;
    hi = n;
    while (lo < hi) { int mid = (lo + hi) >> 1; if (batch[mid] < g + 1) lo = mid + 1; else hi = mid; }
    int end = lo;
    float sum = 0.0f;
    for (int nn = start; nn < end; nn++) sum += h2[(size_t)nn * 64 + f];
    float cnt = (float)(end - start);
    pooled[g * 64 + f] = sum / fmaxf(cnt, 1.0f);
}

__global__ __launch_bounds__(64) void final_gemm(const float* __restrict__ pooled,
                                                 const float* __restrict__ Wl,
                                                 const float* __restrict__ bl,
                                                 float* __restrict__ out) {
    int g = blockIdx.x;
    int f = threadIdx.x;
    float acc = bl[f];
    #pragma unroll 4
    for (int k = 0; k < 64; k++) acc += pooled[g * 64 + k] * Wl[k * 64 + f];
    out[g * 64 + f] = acc;
}

// ---------------- launch ----------------

extern "C" void kernel_launch(void* const* d_in, const int* in_sizes, int n_in,
                              void* d_out, int out_size, void* d_ws, size_t ws_size,
                              hipStream_t stream) {
    const float* x    = (const float*)d_in[0];
    const int*   eidx = (const int*)d_in[1];
    const int*   batch= (const int*)d_in[2];
    const float* W1   = (const float*)d_in[3];
    const float* b1   = (const float*)d_in[4];
    const float* W2   = (const float*)d_in[5];
    const float* b2   = (const float*)d_in[6];
    const float* Wl   = (const float*)d_in[7];
    const float* bl   = (const float*)d_in[8];
    float* out = (float*)d_out;

    const int n_nodes  = in_sizes[0] / FEAT1;     // 50000
    const int n_edges  = in_sizes[1] / 2;         // 800000
    const int n_graphs = out_size / FEAT2;        // 512
    const int* esrc = eidx;
    const int* edst = eidx + n_edges;
    const int nb = (n_nodes + 255) >> 8;          // 196 buckets

    // workspace layout
    char* ws = (char*)d_ws;
    size_t off = 0;
    auto alloc = [&](size_t bytes) -> void* {
        void* p = ws + off;
        off += (bytes + 255) & ~(size_t)255;
        return p;
    };
    __half* t1       = (__half*)alloc((size_t)n_nodes * FEAT1 * 2);  // fp16 scaled table
    float*  hb       = (float*)alloc((size_t)n_nodes * FEAT1 * 4);   // h (f32), reused as h2
    float*  dinv     = (float*)alloc((size_t)n_nodes * 4);
    int2*   nodeinfo = (int2*)alloc((size_t)n_nodes * 8);
    int*    bcur     = (int*)alloc((size_t)nb * 4);
    int*    ebin     = (int*)alloc((size_t)nb * BCAP * 4);
    int*    csr      = (int*)alloc((size_t)nb * BCAP * 4);
    float*  pooled   = (float*)alloc((size_t)n_graphs * FEAT2 * 4);

    // 1. bucketed CSR build (also produces nodeinfo + dinv)
    binit_kernel<<<(nb + 255) / 256, 256, 0, stream>>>(bcur, nb);
    bin_scatter<<<(n_edges + 8191) / 8192, 256, 0, stream>>>(esrc, edst, n_edges, nb, bcur, ebin);
    bucket_csr<<<nb, 256, 0, stream>>>(ebin, bcur, n_nodes, csr, nodeinfo, dinv);

    // 2. layer 1: t1 = fp16((x @ W1) * dinv) ; h = relu(agg(t1)*dinv + b1)
    gemm_tile_h<FEAT1><<<((n_nodes + 63) / 64) * (FEAT1 / 64), 256, 0, stream>>>(x, W1, dinv, t1, n_nodes);
    aggregate_h<FEAT1, true><<<(n_nodes + 3) / 4, 256, 0, stream>>>(t1, dinv, nodeinfo, csr, b1, hb, n_nodes);

    // 3. layer 2: t2 = fp16((h @ W2) * dinv) ; h2 = agg(t2)*dinv + b2
    gemm_tile_h<FEAT2><<<((n_nodes + 63) / 64) * (FEAT2 / 64), 256, 0, stream>>>(hb, W2, dinv, t1, n_nodes);
    aggregate_h<FEAT2, false><<<(n_nodes + 3) / 4, 256, 0, stream>>>(t1, dinv, nodeinfo, csr, b2, hb, n_nodes);

    // 4. mean pool per graph + classifier
    pool_kernel<<<n_graphs, 64, 0, stream>>>(hb, batch, n_nodes, pooled);
    final_gemm<<<n_graphs, 64, 0, stream>>>(pooled, Wl, bl, out);
}

// Round 5
// 181.609 us; speedup vs baseline: 1.9176x; 1.1758x over previous
//
#include <hip/hip_runtime.h>
#include <hip/hip_fp16.h>
#include <math.h>

// GCN forward: h1 = relu(norm_agg(x@W1)+b1); h2 = norm_agg(h1@W2)+b2;
// g = mean_pool(h2, batch); out = g@Wl + bl.
// norm_agg = D^-1/2 (A+I) D^-1/2, CSR-by-dst pull.
// R3: GEMM writes t_scaled[i] = (in@W)[i]*dinv[i] as FP16 -> aggregate is a
//     pure fp16 row-sum gather.
// R4: CSR via 2-pass bucketed counting sort (bucket = dst>>8) -> each csr line
//     written by one block (killed 16x write amplification).
// R5: pooling rewritten as 4-wave blocks (was 1 wave/graph = 3.9% occupancy,
//     41.5 us) with the 64x64 classifier fused in-block from LDS.

#define FEAT1 128
#define FEAT2 64
#define BCAP 8192   // edge capacity per bucket; avg load = 4096

// ---------------- bucketed CSR build ----------------

__global__ void binit_kernel(int* __restrict__ bucket_cursor, int nb) {
    int b = blockIdx.x * 256 + threadIdx.x;
    if (b < nb) bucket_cursor[b] = b * BCAP;
}

// pass 1: scatter edges into per-bucket regions, packed src | ((dst&255)<<18)
__global__ __launch_bounds__(256) void bin_scatter(const int* __restrict__ esrc,
                                                   const int* __restrict__ edst,
                                                   int ne, int nb,
                                                   int* __restrict__ bucket_cursor,
                                                   int* __restrict__ ebin) {
    __shared__ int lcnt[256];
    __shared__ int lcur[256];
    const int tid = threadIdx.x;
    const int e0 = blockIdx.x * 8192;
    lcnt[tid] = 0;
    __syncthreads();
    #pragma unroll 4
    for (int k = 0; k < 32; k++) {
        int e = e0 + k * 256 + tid;
        if (e < ne) atomicAdd(&lcnt[edst[e] >> 8], 1);
    }
    __syncthreads();
    if (tid < nb && lcnt[tid] > 0)
        lcur[tid] = atomicAdd(&bucket_cursor[tid], lcnt[tid]);
    __syncthreads();
    #pragma unroll 4
    for (int k = 0; k < 32; k++) {
        int e = e0 + k * 256 + tid;
        if (e < ne) {
            int d = edst[e];
            int b = d >> 8;
            int p = atomicAdd(&lcur[b], 1);
            if (p < (b + 1) * BCAP)                    // capacity guard
                ebin[p] = esrc[e] | ((d & 255) << 18); // src < 2^17
        }
    }
}

// pass 2: one block per bucket: LDS counts -> scan -> nodeinfo+dinv -> ticket fill
__global__ __launch_bounds__(256) void bucket_csr(const int* __restrict__ ebin,
                                                  const int* __restrict__ bucket_cursor,
                                                  int n_nodes,
                                                  int* __restrict__ csr,
                                                  int2* __restrict__ nodeinfo,
                                                  float* __restrict__ dinv) {
    __shared__ int lcnt[256];
    __shared__ int lscan[256];
    __shared__ int lcur[256];
    const int b = blockIdx.x;
    const int tid = threadIdx.x;
    const int ebeg = b * BCAP;
    int eend = bucket_cursor[b];
    if (eend > ebeg + BCAP) eend = ebeg + BCAP;
    lcnt[tid] = 0;
    __syncthreads();
    for (int e = ebeg + tid; e < eend; e += 256)
        atomicAdd(&lcnt[(ebin[e] >> 18) & 255], 1);
    __syncthreads();
    int v = lcnt[tid];
    lscan[tid] = v;
    __syncthreads();
    for (int off = 1; off < 256; off <<= 1) {
        int u = (tid >= off) ? lscan[tid - off] : 0;
        __syncthreads();
        lscan[tid] += u;
        __syncthreads();
    }
    const int start = ebeg + (lscan[tid] - v);   // exclusive scan position
    const int node = (b << 8) + tid;
    if (node < n_nodes) {
        nodeinfo[node] = make_int2(start, v);
        dinv[node] = (float)(1.0 / sqrt((double)(v + 1)));  // +1 self loop
    }
    lcur[tid] = start;
    __syncthreads();
    for (int e = ebeg + tid; e < eend; e += 256) {
        int pk = ebin[e];
        int p = atomicAdd(&lcur[(pk >> 18) & 255], 1);
        csr[p] = pk & 0x3FFFF;
    }
}

// ---------------- tiled dense GEMM with fp16+dinv-scaled output ----------------
// t_out[row, c] = fp16( (A[row,:] @ W[:,c]) * dinv[row] )
template <int FOUT>
__global__ __launch_bounds__(256) void gemm_tile_h(const float* __restrict__ A,
                                                   const float* __restrict__ W,
                                                   const float* __restrict__ dinv,
                                                   __half* __restrict__ out, int n) {
    __shared__ float As[64][36];
    __shared__ float Ws[32][68];
    const int tid = threadIdx.x;
    constexpr int NCT = FOUT / 64;
    const int row0 = (blockIdx.x / NCT) * 64;
    const int col0 = (blockIdx.x % NCT) * 64;
    const int rg = tid >> 4;
    const int cg = tid & 15;

    float acc[4][4] = {};

    for (int k0 = 0; k0 < 128; k0 += 32) {
        {
            int r = tid >> 2;
            int k = (tid & 3) * 8;
            int grow = row0 + r;
            float4 v0 = {0.f, 0.f, 0.f, 0.f}, v1 = {0.f, 0.f, 0.f, 0.f};
            if (grow < n) {
                const float* p = A + (size_t)grow * 128 + k0 + k;
                v0 = *(const float4*)(p);
                v1 = *(const float4*)(p + 4);
            }
            *(float4*)(&As[r][k])     = v0;
            *(float4*)(&As[r][k + 4]) = v1;
        }
        {
            int k = tid >> 3;
            int c = (tid & 7) * 8;
            const float* p = W + (size_t)(k0 + k) * FOUT + col0 + c;
            *(float4*)(&Ws[k][c])     = *(const float4*)(p);
            *(float4*)(&Ws[k][c + 4]) = *(const float4*)(p + 4);
        }
        __syncthreads();

        #pragma unroll 8
        for (int k = 0; k < 32; k++) {
            float4 w = *(const float4*)(&Ws[k][cg * 4]);
            float ar0 = As[rg * 4 + 0][k];
            float ar1 = As[rg * 4 + 1][k];
            float ar2 = As[rg * 4 + 2][k];
            float ar3 = As[rg * 4 + 3][k];
            acc[0][0] += ar0 * w.x; acc[0][1] += ar0 * w.y; acc[0][2] += ar0 * w.z; acc[0][3] += ar0 * w.w;
            acc[1][0] += ar1 * w.x; acc[1][1] += ar1 * w.y; acc[1][2] += ar1 * w.z; acc[1][3] += ar1 * w.w;
            acc[2][0] += ar2 * w.x; acc[2][1] += ar2 * w.y; acc[2][2] += ar2 * w.z; acc[2][3] += ar2 * w.w;
            acc[3][0] += ar3 * w.x; acc[3][1] += ar3 * w.y; acc[3][2] += ar3 * w.z; acc[3][3] += ar3 * w.w;
        }
        __syncthreads();
    }

    #pragma unroll
    for (int rr = 0; rr < 4; rr++) {
        int grow = row0 + rg * 4 + rr;
        if (grow < n) {
            float s = dinv[grow];
            __half2 h01 = __floats2half2_rn(acc[rr][0] * s, acc[rr][1] * s);
            __half2 h23 = __floats2half2_rn(acc[rr][2] * s, acc[rr][3] * s);
            __half2* p = (__half2*)(out + (size_t)grow * FOUT + col0 + cg * 4);
            p[0] = h01;
            p[1] = h23;
        }
    }
}

// ---------------- normalized aggregation: pure fp16 row-sum gather ----------------
// out[i] = relu?( (sum_{s in N(i) u {i}} t_scaled[s]) * dinv[i] + b )
template <int F, bool RELU>
__global__ __launch_bounds__(256) void aggregate_h(const __half* __restrict__ t,
                                                   const float* __restrict__ dinv,
                                                   const int2* __restrict__ nodeinfo,
                                                   const int* __restrict__ csr_src,
                                                   const float* __restrict__ bias,
                                                   float* __restrict__ out, int n) {
    const int wv = threadIdx.x >> 6;
    const int lane = threadIdx.x & 63;
    const int i = blockIdx.x * 4 + wv;
    if (i >= n) return;
    const float di = dinv[i];
    const int2 ni = nodeinfo[i];
    const int e0 = ni.x, e1 = ni.x + ni.y;

    if constexpr (F == 128) {
        float2 a0, a1 = {0.f, 0.f}, a2 = {0.f, 0.f}, a3 = {0.f, 0.f};
        a0 = __half22float2(((const __half2*)(t + (size_t)i * F))[lane]);  // self
        int e = e0;
        for (; e + 4 <= e1; e += 4) {
            int s0 = csr_src[e + 0], s1 = csr_src[e + 1], s2 = csr_src[e + 2], s3 = csr_src[e + 3];
            float2 v0 = __half22float2(((const __half2*)(t + (size_t)s0 * F))[lane]);
            float2 v1 = __half22float2(((const __half2*)(t + (size_t)s1 * F))[lane]);
            float2 v2 = __half22float2(((const __half2*)(t + (size_t)s2 * F))[lane]);
            float2 v3 = __half22float2(((const __half2*)(t + (size_t)s3 * F))[lane]);
            a0.x += v0.x; a0.y += v0.y;
            a1.x += v1.x; a1.y += v1.y;
            a2.x += v2.x; a2.y += v2.y;
            a3.x += v3.x; a3.y += v3.y;
        }
        for (; e < e1; e++) {
            int s = csr_src[e];
            float2 v = __half22float2(((const __half2*)(t + (size_t)s * F))[lane]);
            a0.x += v.x; a0.y += v.y;
        }
        float2 b = ((const float2*)bias)[lane];
        float rx = (a0.x + a1.x + a2.x + a3.x) * di + b.x;
        float ry = (a0.y + a1.y + a2.y + a3.y) * di + b.y;
        if (RELU) { rx = fmaxf(rx, 0.f); ry = fmaxf(ry, 0.f); }
        ((float2*)(out + (size_t)i * F))[lane] = make_float2(rx, ry);
    } else {
        float a0, a1 = 0.f, a2 = 0.f, a3 = 0.f;
        a0 = __half2float(t[(size_t)i * F + lane]);  // self
        int e = e0;
        for (; e + 4 <= e1; e += 4) {
            int s0 = csr_src[e + 0], s1 = csr_src[e + 1], s2 = csr_src[e + 2], s3 = csr_src[e + 3];
            float v0 = __half2float(t[(size_t)s0 * F + lane]);
            float v1 = __half2float(t[(size_t)s1 * F + lane]);
            float v2 = __half2float(t[(size_t)s2 * F + lane]);
            float v3 = __half2float(t[(size_t)s3 * F + lane]);
            a0 += v0; a1 += v1; a2 += v2; a3 += v3;
        }
        for (; e < e1; e++) {
            a0 += __half2float(t[(size_t)csr_src[e] * F + lane]);
        }
        float r = (a0 + a1 + a2 + a3) * di + bias[lane];
        if (RELU) r = fmaxf(r, 0.f);
        out[(size_t)i * F + lane] = r;
    }
}

// ---------------- fused mean-pool + classifier ----------------
// One 4-wave block per graph: waves stride rows (4 gathers in flight),
// LDS cross-wave reduce, then out[g] = pooled @ Wl + bl from LDS.
__global__ __launch_bounds__(256) void pool_classify(const float* __restrict__ h2,
                                                     const int* __restrict__ batch, int n,
                                                     const float* __restrict__ Wl,
                                                     const float* __restrict__ bl,
                                                     float* __restrict__ out) {
    __shared__ float partial[4][64];
    __shared__ float pooled_s[64];
    const int g = blockIdx.x;
    const int wv = threadIdx.x >> 6;
    const int lane = threadIdx.x & 63;

    // graph boundaries in sorted batch (redundant per-thread, cheap: L2-hot)
    int lo = 0, hi = n;
    while (lo < hi) { int mid = (lo + hi) >> 1; if (batch[mid] < g) lo = mid + 1; else hi = mid; }
    const int start = lo;
    hi = n;
    while (lo < hi) { int mid = (lo + hi) >> 1; if (batch[mid] < g + 1) lo = mid + 1; else hi = mid; }
    const int end = lo;

    float sum = 0.0f;
    int r = start + wv;
    for (; r + 8 <= end; r += 8) {                // 2 rows in flight per wave
        float v0 = h2[(size_t)r * 64 + lane];
        float v1 = h2[(size_t)(r + 4) * 64 + lane];
        sum += v0 + v1;
    }
    for (; r < end; r += 4) sum += h2[(size_t)r * 64 + lane];
    partial[wv][lane] = sum;
    __syncthreads();

    if (wv == 0) {
        float s = partial[0][lane] + partial[1][lane] + partial[2][lane] + partial[3][lane];
        float cnt = (float)(end - start);
        pooled_s[lane] = s / fmaxf(cnt, 1.0f);
    }
    __syncthreads();

    if (wv == 0) {
        float acc = bl[lane];
        #pragma unroll 8
        for (int k = 0; k < 64; k++) acc += pooled_s[k] * Wl[k * 64 + lane];
        out[(size_t)g * 64 + lane] = acc;
    }
}

// ---------------- launch ----------------

extern "C" void kernel_launch(void* const* d_in, const int* in_sizes, int n_in,
                              void* d_out, int out_size, void* d_ws, size_t ws_size,
                              hipStream_t stream) {
    const float* x    = (const float*)d_in[0];
    const int*   eidx = (const int*)d_in[1];
    const int*   batch= (const int*)d_in[2];
    const float* W1   = (const float*)d_in[3];
    const float* b1   = (const float*)d_in[4];
    const float* W2   = (const float*)d_in[5];
    const float* b2   = (const float*)d_in[6];
    const float* Wl   = (const float*)d_in[7];
    const float* bl   = (const float*)d_in[8];
    float* out = (float*)d_out;

    const int n_nodes  = in_sizes[0] / FEAT1;     // 50000
    const int n_edges  = in_sizes[1] / 2;         // 800000
    const int n_graphs = out_size / FEAT2;        // 512
    const int* esrc = eidx;
    const int* edst = eidx + n_edges;
    const int nb = (n_nodes + 255) >> 8;          // 196 buckets

    // workspace layout
    char* ws = (char*)d_ws;
    size_t off = 0;
    auto alloc = [&](size_t bytes) -> void* {
        void* p = ws + off;
        off += (bytes + 255) & ~(size_t)255;
        return p;
    };
    __half* t1       = (__half*)alloc((size_t)n_nodes * FEAT1 * 2);  // fp16 scaled table
    float*  hb       = (float*)alloc((size_t)n_nodes * FEAT1 * 4);   // h (f32), reused as h2
    float*  dinv     = (float*)alloc((size_t)n_nodes * 4);
    int2*   nodeinfo = (int2*)alloc((size_t)n_nodes * 8);
    int*    bcur     = (int*)alloc((size_t)nb * 4);
    int*    ebin     = (int*)alloc((size_t)nb * BCAP * 4);
    int*    csr      = (int*)alloc((size_t)nb * BCAP * 4);

    // 1. bucketed CSR build (also produces nodeinfo + dinv)
    binit_kernel<<<(nb + 255) / 256, 256, 0, stream>>>(bcur, nb);
    bin_scatter<<<(n_edges + 8191) / 8192, 256, 0, stream>>>(esrc, edst, n_edges, nb, bcur, ebin);
    bucket_csr<<<nb, 256, 0, stream>>>(ebin, bcur, n_nodes, csr, nodeinfo, dinv);

    // 2. layer 1: t1 = fp16((x @ W1) * dinv) ; h = relu(agg(t1)*dinv + b1)
    gemm_tile_h<FEAT1><<<((n_nodes + 63) / 64) * (FEAT1 / 64), 256, 0, stream>>>(x, W1, dinv, t1, n_nodes);
    aggregate_h<FEAT1, true><<<(n_nodes + 3) / 4, 256, 0, stream>>>(t1, dinv, nodeinfo, csr, b1, hb, n_nodes);

    // 3. layer 2: t2 = fp16((h @ W2) * dinv) ; h2 = agg(t2)*dinv + b2
    gemm_tile_h<FEAT2><<<((n_nodes + 63) / 64) * (FEAT2 / 64), 256, 0, stream>>>(hb, W2, dinv, t1, n_nodes);
    aggregate_h<FEAT2, false><<<(n_nodes + 3) / 4, 256, 0, stream>>>(t1, dinv, nodeinfo, csr, b2, hb, n_nodes);

    // 4. fused mean pool + classifier
    pool_classify<<<n_graphs, 256, 0, stream>>>(hb, batch, n_nodes, Wl, bl, out);
}

// Round 6
// 169.468 us; speedup vs baseline: 2.0550x; 1.0716x over previous
//
#include <hip/hip_runtime.h>
#include <hip/hip_fp16.h>
#include <math.h>

// GCN forward: h1 = relu(norm_agg(x@W1)+b1); h2 = norm_agg(h1@W2)+b2;
// g = mean_pool(h2, batch); out = g@Wl + bl.
// norm_agg = D^-1/2 (A+I) D^-1/2, CSR-by-dst pull.
// R3: GEMM writes t_scaled[i] = (in@W)[i]*dinv[i] as FP16 -> aggregate is a
//     pure fp16 row-sum gather.
// R4: CSR via 2-pass bucketed counting sort (one block owns each csr line).
// R5: pooling as 4-wave blocks with fused classifier.
// R6: GEMMs use MFMA (fp16 LDS staging, mfma_f32_16x16x32_f16, 128x64 tile);
//     agg1 writes h1 as fp16 (gemm2 restages fp16 anyway -> same rounding);
//     binit folded into hipMemsetAsync + bucket-relative cursors.

#define FEAT1 128
#define FEAT2 64
#define BCAP 8192   // edge capacity per bucket; avg load = 4096

using half8 = __attribute__((ext_vector_type(8))) _Float16;
using half4 = __attribute__((ext_vector_type(4))) _Float16;
using f32x4 = __attribute__((ext_vector_type(4))) float;

// ---------------- bucketed CSR build ----------------

// pass 1: scatter edges into per-bucket regions, packed src | ((dst&255)<<18)
// bucket_cursor holds RELATIVE fill counts (memset to 0 before launch).
__global__ __launch_bounds__(256) void bin_scatter(const int* __restrict__ esrc,
                                                   const int* __restrict__ edst,
                                                   int ne, int nb,
                                                   int* __restrict__ bucket_cursor,
                                                   int* __restrict__ ebin) {
    __shared__ int lcnt[256];
    __shared__ int lcur[256];
    const int tid = threadIdx.x;
    const int e0 = blockIdx.x * 8192;
    lcnt[tid] = 0;
    __syncthreads();
    #pragma unroll 4
    for (int k = 0; k < 32; k++) {
        int e = e0 + k * 256 + tid;
        if (e < ne) atomicAdd(&lcnt[edst[e] >> 8], 1);
    }
    __syncthreads();
    if (tid < nb && lcnt[tid] > 0)
        lcur[tid] = atomicAdd(&bucket_cursor[tid], lcnt[tid]);
    __syncthreads();
    #pragma unroll 4
    for (int k = 0; k < 32; k++) {
        int e = e0 + k * 256 + tid;
        if (e < ne) {
            int d = edst[e];
            int b = d >> 8;
            int p = atomicAdd(&lcur[b], 1);          // relative position
            if (p < BCAP)                            // capacity guard
                ebin[b * BCAP + p] = esrc[e] | ((d & 255) << 18); // src < 2^17
        }
    }
}

// pass 2: one block per bucket: LDS counts -> scan -> nodeinfo+dinv -> ticket fill
__global__ __launch_bounds__(256) void bucket_csr(const int* __restrict__ ebin,
                                                  const int* __restrict__ bucket_cursor,
                                                  int n_nodes,
                                                  int* __restrict__ csr,
                                                  int2* __restrict__ nodeinfo,
                                                  float* __restrict__ dinv) {
    __shared__ int lcnt[256];
    __shared__ int lscan[256];
    __shared__ int lcur[256];
    const int b = blockIdx.x;
    const int tid = threadIdx.x;
    const int ebeg = b * BCAP;
    int cnt_b = bucket_cursor[b];
    if (cnt_b > BCAP) cnt_b = BCAP;
    const int eend = ebeg + cnt_b;
    lcnt[tid] = 0;
    __syncthreads();
    for (int e = ebeg + tid; e < eend; e += 256)
        atomicAdd(&lcnt[(ebin[e] >> 18) & 255], 1);
    __syncthreads();
    int v = lcnt[tid];
    lscan[tid] = v;
    __syncthreads();
    for (int off = 1; off < 256; off <<= 1) {
        int u = (tid >= off) ? lscan[tid - off] : 0;
        __syncthreads();
        lscan[tid] += u;
        __syncthreads();
    }
    const int start = ebeg + (lscan[tid] - v);   // exclusive scan position
    const int node = (b << 8) + tid;
    if (node < n_nodes) {
        nodeinfo[node] = make_int2(start, v);
        dinv[node] = (float)(1.0 / sqrt((double)(v + 1)));  // +1 self loop
    }
    lcur[tid] = start;
    __syncthreads();
    for (int e = ebeg + tid; e < eend; e += 256) {
        int pk = ebin[e];
        int p = atomicAdd(&lcur[(pk >> 18) & 255], 1);
        csr[p] = pk & 0x3FFFF;
    }
}

// ---------------- MFMA GEMM with fp16+dinv-scaled output ----------------
// t_out[row, c] = fp16( (A[row,:128] @ W[:128,c]) * dinv[row] )
// Block: 256 thr = 4 waves; tile 128 rows x 64 cols; full K=128 in LDS fp16.
// Padded LDS stride 136 halves (272 B): row-to-row bank shift of 4 words ->
// b128 fragment reads are ~2-way (free). mfma_f32_16x16x32_f16, per wave:
// 2 M-subtiles x 4 N-subtiles, K in 4 steps.
template <int FOUT, bool A_F16>
__global__ __launch_bounds__(256) void gemm_mfma(const void* __restrict__ Aptr,
                                                 const float* __restrict__ W,
                                                 const float* __restrict__ dinv,
                                                 _Float16* __restrict__ out, int n) {
    __shared__ _Float16 As[128 * 136];
    __shared__ _Float16 Ws[64 * 136];
    const int tid = threadIdx.x;
    const int wv = tid >> 6;
    const int lane = tid & 63;
    constexpr int NCT = FOUT / 64;
    const int row0 = (blockIdx.x / NCT) * 128;
    const int col0 = (blockIdx.x % NCT) * 64;

    // stage A: 128 rows x 128 k, 2 threads/row (64 cols each), fp32->fp16
    {
        const int r = tid >> 1;
        const int c0 = (tid & 1) * 64;
        const int grow = row0 + r;
        if constexpr (A_F16) {
            const _Float16* A = (const _Float16*)Aptr + (size_t)grow * 128 + c0;
            #pragma unroll
            for (int j = 0; j < 8; j++) {
                half8 v = {};
                if (grow < n) v = *(const half8*)(A + j * 8);
                *(half8*)(&As[r * 136 + c0 + j * 8]) = v;
            }
        } else {
            const float* A = (const float*)Aptr + (size_t)grow * 128 + c0;
            #pragma unroll
            for (int j = 0; j < 16; j++) {
                float4 v = {0.f, 0.f, 0.f, 0.f};
                if (grow < n) v = *(const float4*)(A + j * 4);
                half4 hv = {(_Float16)v.x, (_Float16)v.y, (_Float16)v.z, (_Float16)v.w};
                *(half4*)(&As[r * 136 + c0 + j * 4]) = hv;
            }
        }
    }
    // stage W transposed: Ws[col][k], 2 threads/k-row (32 cols each)
    {
        const int k = tid >> 1;
        const int cb = (tid & 1) * 32;
        #pragma unroll
        for (int j = 0; j < 8; j++) {
            int c = cb + j * 4;
            float4 v = *(const float4*)(W + (size_t)k * FOUT + col0 + c);
            Ws[(c + 0) * 136 + k] = (_Float16)v.x;
            Ws[(c + 1) * 136 + k] = (_Float16)v.y;
            Ws[(c + 2) * 136 + k] = (_Float16)v.z;
            Ws[(c + 3) * 136 + k] = (_Float16)v.w;
        }
    }
    __syncthreads();

    f32x4 acc[2][4] = {};
    const int mrow = wv * 32 + (lane & 15);
    const int kb = (lane >> 4) * 8;
    #pragma unroll
    for (int ks = 0; ks < 4; ks++) {
        const int kk = ks * 32 + kb;
        half8 a0 = *(const half8*)(&As[mrow * 136 + kk]);
        half8 a1 = *(const half8*)(&As[(mrow + 16) * 136 + kk]);
        #pragma unroll
        for (int nj = 0; nj < 4; nj++) {
            half8 b = *(const half8*)(&Ws[(nj * 16 + (lane & 15)) * 136 + kk]);
            acc[0][nj] = __builtin_amdgcn_mfma_f32_16x16x32_f16(a0, b, acc[0][nj], 0, 0, 0);
            acc[1][nj] = __builtin_amdgcn_mfma_f32_16x16x32_f16(a1, b, acc[1][nj], 0, 0, 0);
        }
    }

    // C/D layout: col = lane&15, row = (lane>>4)*4 + reg
    #pragma unroll
    for (int mi = 0; mi < 2; mi++) {
        const int gr0 = row0 + wv * 32 + mi * 16 + (lane >> 4) * 4;
        #pragma unroll
        for (int r = 0; r < 4; r++) {
            const int grow = gr0 + r;
            if (grow < n) {
                const float s = dinv[grow];
                #pragma unroll
                for (int nj = 0; nj < 4; nj++) {
                    out[(size_t)grow * FOUT + col0 + nj * 16 + (lane & 15)] =
                        (_Float16)(acc[mi][nj][r] * s);
                }
            }
        }
    }
}

// ---------------- normalized aggregation: pure fp16 row-sum gather ----------------
// out[i] = relu?( (sum_{s in N(i) u {i}} t_scaled[s]) * dinv[i] + b )
template <int F, bool RELU, bool OUT16>
__global__ __launch_bounds__(256) void aggregate_h(const __half* __restrict__ t,
                                                   const float* __restrict__ dinv,
                                                   const int2* __restrict__ nodeinfo,
                                                   const int* __restrict__ csr_src,
                                                   const float* __restrict__ bias,
                                                   void* __restrict__ outp, int n) {
    const int wv = threadIdx.x >> 6;
    const int lane = threadIdx.x & 63;
    const int i = blockIdx.x * 4 + wv;
    if (i >= n) return;
    const float di = dinv[i];
    const int2 ni = nodeinfo[i];
    const int e0 = ni.x, e1 = ni.x + ni.y;

    if constexpr (F == 128) {
        float2 a0, a1 = {0.f, 0.f}, a2 = {0.f, 0.f}, a3 = {0.f, 0.f};
        a0 = __half22float2(((const __half2*)(t + (size_t)i * F))[lane]);  // self
        int e = e0;
        for (; e + 4 <= e1; e += 4) {
            int s0 = csr_src[e + 0], s1 = csr_src[e + 1], s2 = csr_src[e + 2], s3 = csr_src[e + 3];
            float2 v0 = __half22float2(((const __half2*)(t + (size_t)s0 * F))[lane]);
            float2 v1 = __half22float2(((const __half2*)(t + (size_t)s1 * F))[lane]);
            float2 v2 = __half22float2(((const __half2*)(t + (size_t)s2 * F))[lane]);
            float2 v3 = __half22float2(((const __half2*)(t + (size_t)s3 * F))[lane]);
            a0.x += v0.x; a0.y += v0.y;
            a1.x += v1.x; a1.y += v1.y;
            a2.x += v2.x; a2.y += v2.y;
            a3.x += v3.x; a3.y += v3.y;
        }
        for (; e < e1; e++) {
            int s = csr_src[e];
            float2 v = __half22float2(((const __half2*)(t + (size_t)s * F))[lane]);
            a0.x += v.x; a0.y += v.y;
        }
        float2 b = ((const float2*)bias)[lane];
        float rx = (a0.x + a1.x + a2.x + a3.x) * di + b.x;
        float ry = (a0.y + a1.y + a2.y + a3.y) * di + b.y;
        if (RELU) { rx = fmaxf(rx, 0.f); ry = fmaxf(ry, 0.f); }
        if constexpr (OUT16) {
            ((__half2*)((__half*)outp + (size_t)i * F))[lane] = __floats2half2_rn(rx, ry);
        } else {
            ((float2*)((float*)outp + (size_t)i * F))[lane] = make_float2(rx, ry);
        }
    } else {
        float a0, a1 = 0.f, a2 = 0.f, a3 = 0.f;
        a0 = __half2float(t[(size_t)i * F + lane]);  // self
        int e = e0;
        for (; e + 4 <= e1; e += 4) {
            int s0 = csr_src[e + 0], s1 = csr_src[e + 1], s2 = csr_src[e + 2], s3 = csr_src[e + 3];
            float v0 = __half2float(t[(size_t)s0 * F + lane]);
            float v1 = __half2float(t[(size_t)s1 * F + lane]);
            float v2 = __half2float(t[(size_t)s2 * F + lane]);
            float v3 = __half2float(t[(size_t)s3 * F + lane]);
            a0 += v0; a1 += v1; a2 += v2; a3 += v3;
        }
        for (; e < e1; e++) {
            a0 += __half2float(t[(size_t)csr_src[e] * F + lane]);
        }
        float r = (a0 + a1 + a2 + a3) * di + bias[lane];
        if (RELU) r = fmaxf(r, 0.f);
        if constexpr (OUT16) {
            ((__half*)outp)[(size_t)i * F + lane] = __float2half(r);
        } else {
            ((float*)outp)[(size_t)i * F + lane] = r;
        }
    }
}

// ---------------- fused mean-pool + classifier ----------------
__global__ __launch_bounds__(256) void pool_classify(const float* __restrict__ h2,
                                                     const int* __restrict__ batch, int n,
                                                     const float* __restrict__ Wl,
                                                     const float* __restrict__ bl,
                                                     float* __restrict__ out) {
    __shared__ float partial[4][64];
    __shared__ float pooled_s[64];
    const int g = blockIdx.x;
    const int wv = threadIdx.x >> 6;
    const int lane = threadIdx.x & 63;

    int lo = 0, hi = n;
    while (lo < hi) { int mid = (lo + hi) >> 1; if (batch[mid] < g) lo = mid + 1; else hi = mid; }
    const int start = lo;
    hi = n;
    while (lo < hi) { int mid = (lo + hi) >> 1; if (batch[mid] < g + 1) lo = mid + 1; else hi = mid; }
    const int end = lo;

    float sum = 0.0f;
    int r = start + wv;
    for (; r + 8 <= end; r += 8) {
        float v0 = h2[(size_t)r * 64 + lane];
        float v1 = h2[(size_t)(r + 4) * 64 + lane];
        sum += v0 + v1;
    }
    for (; r < end; r += 4) sum += h2[(size_t)r * 64 + lane];
    partial[wv][lane] = sum;
    __syncthreads();

    if (wv == 0) {
        float s = partial[0][lane] + partial[1][lane] + partial[2][lane] + partial[3][lane];
        float cnt = (float)(end - start);
        pooled_s[lane] = s / fmaxf(cnt, 1.0f);
    }
    __syncthreads();

    if (wv == 0) {
        float acc = bl[lane];
        #pragma unroll 8
        for (int k = 0; k < 64; k++) acc += pooled_s[k] * Wl[k * 64 + lane];
        out[(size_t)g * 64 + lane] = acc;
    }
}

// ---------------- launch ----------------

extern "C" void kernel_launch(void* const* d_in, const int* in_sizes, int n_in,
                              void* d_out, int out_size, void* d_ws, size_t ws_size,
                              hipStream_t stream) {
    const float* x    = (const float*)d_in[0];
    const int*   eidx = (const int*)d_in[1];
    const int*   batch= (const int*)d_in[2];
    const float* W1   = (const float*)d_in[3];
    const float* b1   = (const float*)d_in[4];
    const float* W2   = (const float*)d_in[5];
    const float* b2   = (const float*)d_in[6];
    const float* Wl   = (const float*)d_in[7];
    const float* bl   = (const float*)d_in[8];
    float* out = (float*)d_out;

    const int n_nodes  = in_sizes[0] / FEAT1;     // 50000
    const int n_edges  = in_sizes[1] / 2;         // 800000
    const int n_graphs = out_size / FEAT2;        // 512
    const int* esrc = eidx;
    const int* edst = eidx + n_edges;
    const int nb = (n_nodes + 255) >> 8;          // 196 buckets

    // workspace layout
    char* ws = (char*)d_ws;
    size_t off = 0;
    auto alloc = [&](size_t bytes) -> void* {
        void* p = ws + off;
        off += (bytes + 255) & ~(size_t)255;
        return p;
    };
    _Float16* t1     = (_Float16*)alloc((size_t)n_nodes * FEAT1 * 2); // fp16 scaled table (reused as t2)
    __half*   h1h    = (__half*)alloc((size_t)n_nodes * FEAT1 * 2);   // fp16 h1 (agg1 out, gemm2 in)
    float*    h2     = (float*)alloc((size_t)n_nodes * FEAT2 * 4);    // f32 h2 (agg2 out, pool in)
    float*    dinv   = (float*)alloc((size_t)n_nodes * 4);
    int2*   nodeinfo = (int2*)alloc((size_t)n_nodes * 8);
    int*    bcur     = (int*)alloc((size_t)nb * 4);
    int*    ebin     = (int*)alloc((size_t)nb * BCAP * 4);
    int*    csr      = (int*)alloc((size_t)nb * BCAP * 4);

    const int nrb = (n_nodes + 127) / 128;        // 391 row-tiles

    // 1. bucketed CSR build (also produces nodeinfo + dinv)
    hipMemsetAsync(bcur, 0, (size_t)nb * 4, stream);
    bin_scatter<<<(n_edges + 8191) / 8192, 256, 0, stream>>>(esrc, edst, n_edges, nb, bcur, ebin);
    bucket_csr<<<nb, 256, 0, stream>>>(ebin, bcur, n_nodes, csr, nodeinfo, dinv);

    // 2. layer 1: t1 = fp16((x @ W1) * dinv) ; h1 = fp16(relu(agg(t1)*dinv + b1))
    gemm_mfma<FEAT1, false><<<nrb * (FEAT1 / 64), 256, 0, stream>>>(x, W1, dinv, t1, n_nodes);
    aggregate_h<FEAT1, true, true><<<(n_nodes + 3) / 4, 256, 0, stream>>>(
        (const __half*)t1, dinv, nodeinfo, csr, b1, h1h, n_nodes);

    // 3. layer 2: t2 = fp16((h1 @ W2) * dinv) ; h2 = agg(t2)*dinv + b2 (f32)
    gemm_mfma<FEAT2, true><<<nrb * (FEAT2 / 64), 256, 0, stream>>>(h1h, W2, dinv, t1, n_nodes);
    aggregate_h<FEAT2, false, false><<<(n_nodes + 3) / 4, 256, 0, stream>>>(
        (const __half*)t1, dinv, nodeinfo, csr, b2, h2, n_nodes);

    // 4. fused mean pool + classifier
    pool_classify<<<n_graphs, 256, 0, stream>>>(h2, batch, n_nodes, Wl, bl, out);
}